// Round 5
// baseline (408.780 us; speedup 1.0000x reference)
//
#include <hip/hip_runtime.h>

// Sinkhorn (dustbin-augmented) fully fused, iterated in the EXP domain.
//
//   ev_j = 2^{v'_j}, eu_i = 2^{u'_i}, A = 2^{alpha*log2e}, K9 = 2^-9
//   eu_i  = K9 / (sum_j es_ij*ev_j + A*evd)        es_ij = 2^{s_ij*log2e}
//   eud   = (0.5/A) / (sum_j ev_j + evd)
//   ev_j  = K9 / (sum_i es_ij*eu_i + A*eud)
//   evd   = (0.5/A) / (sum_i eu_i + eud)
//   Z     = (log2(es) + log2(eu) + log2(ev) + 9) * ln2
//
// Block = 1024 threads = one batch. Thread (a=t>>5, bb=t&31) owns rows
// [8a,8a+8) x cols {4bb..4bb+3, 128+4bb..128+4bb+3}.
//
// amdgpu_waves_per_eu(4,4): lowers the register allocator's occupancy TARGET
// to 4 waves/SIMD (128-VGPR budget). __launch_bounds__(1024,4) alone only
// capped VGPRs at 128 but LLVM still targeted 8 waves/EU (64 VGPR) and
// spilled the 64-float es tile to scratch (v3/v4: VGPR_Count=64, 910 MB HBM
// fetch from scratch re-reads, 437 us).

#define PS 260  // partial-row stride in floats

constexpr float L2E = 1.4426950408889634f;
constexpr float LN2 = 0.6931471805599453f;
constexpr float K9  = 0.001953125f;  // 2^-9

__device__ __forceinline__ float flog2(float x) { return __builtin_amdgcn_logf(x); }
__device__ __forceinline__ float fexp2(float x) { return __builtin_amdgcn_exp2f(x); }

// classic-DPP fused add (quad_perm / row_ror only — unambiguous GCN semantics)
template <int CTRL>
__device__ __forceinline__ float dpp_add(float x) {
    int y = __builtin_amdgcn_update_dpp(0, __builtin_bit_cast(int, x), CTRL, 0xF, 0xF, true);
    return x + __builtin_bit_cast(float, y);
}

// allreduce over the 32 lanes of a half-wave (the bb dimension)
__device__ __forceinline__ float reduce32(float x) {
    x = dpp_add<0xB1>(x);    // quad_perm [1,0,3,2] : xor 1
    x = dpp_add<0x4E>(x);    // quad_perm [2,3,0,1] : xor 2
    x = dpp_add<0x124>(x);   // row_ror:4           : quad fold
    x = dpp_add<0x128>(x);   // row_ror:8           : row uniform
    x += __shfl_xor(x, 16, 64);  // cross 16 (proven path)
    return x;
}

__device__ __forceinline__ float xor32_add(float x) {
    return x + __shfl_xor(x, 32, 64);  // proven path
}

__global__ __launch_bounds__(1024)
__attribute__((amdgpu_waves_per_eu(4, 4)))
void sinkhorn_kernel(
    const float* __restrict__ scores,
    const float* __restrict__ alpha_p,
    const int*   __restrict__ iters_p,
    float* __restrict__ out)
{
    const int bat = blockIdx.x;
    const int t   = threadIdx.x;
    const int a   = t >> 5;   // row-group: rows [8a, 8a+8)
    const int bb  = t & 31;   // col-group: cols 4bb.. and 128+4bb..
    const int w   = t >> 6;   // wave id 0..15

    const float alpha2    = alpha_p[0] * L2E;
    const float A         = fexp2(alpha2);
    const float halfOverA = fexp2(-1.0f - alpha2);
    const int iters = iters_p[0];

    __shared__ __align__(16) float sbuf[2][16 * PS];  // per-wave column partials
    __shared__ __align__(16) float vbuf[2][PS];       // ev (257 entries used)

    // ---- load scores once; keep es = 2^(s*log2e) in registers ----
    float es[8][8];
    const float* sp = scores + ((size_t)bat << 16) + ((size_t)a << 11) + (bb << 2);
    #pragma unroll
    for (int r = 0; r < 8; ++r) {
        const float4 x0 = *reinterpret_cast<const float4*>(sp + (r << 8));
        const float4 x1 = *reinterpret_cast<const float4*>(sp + (r << 8) + 128);
        es[r][0] = fexp2(x0.x * L2E);
        es[r][1] = fexp2(x0.y * L2E);
        es[r][2] = fexp2(x0.z * L2E);
        es[r][3] = fexp2(x0.w * L2E);
        es[r][4] = fexp2(x1.x * L2E);
        es[r][5] = fexp2(x1.y * L2E);
        es[r][6] = fexp2(x1.z * L2E);
        es[r][7] = fexp2(x1.w * L2E);
    }

    if (t < 257) vbuf[0][t] = 1.0f;   // v0 = 0  ->  ev = 1
    float eul[8];
    #pragma unroll
    for (int r = 0; r < 8; ++r) eul[r] = 1.0f;
    float eud = 1.0f;
    __syncthreads();

    for (int it = 0; it < iters; ++it) {
        const int cur = it & 1, nxt = cur ^ 1;

        // ---------------- row phase: eu from ev ----------------
        const float4 e0 = *reinterpret_cast<const float4*>(&vbuf[cur][bb << 2]);
        const float4 e1 = *reinterpret_cast<const float4*>(&vbuf[cur][128 + (bb << 2)]);
        const float evd = vbuf[cur][256];
        float evl[8] = {e0.x, e0.y, e0.z, e0.w, e1.x, e1.y, e1.z, e1.w};

        float sv = ((evl[0]+evl[1])+(evl[2]+evl[3]))+((evl[4]+evl[5])+(evl[6]+evl[7]));
        sv = reduce32(sv);                       // sum_j ev_j (all 256 cols)
        eud = halfOverA / (sv + evd);

        const float tdv = A * evd;
        #pragma unroll
        for (int r = 0; r < 8; ++r) {
            float p = es[r][0] * evl[0];
            #pragma unroll
            for (int c = 1; c < 8; ++c) p = fmaf(es[r][c], evl[c], p);
            p = reduce32(p);
            eul[r] = K9 / (p + tdv);
        }

        // ---------------- col phase: ev from (new) eu ----------------
        float us = ((eul[0]+eul[1])+(eul[2]+eul[3]))+((eul[4]+eul[5])+(eul[6]+eul[7]));
        float pc[8];
        #pragma unroll
        for (int c = 0; c < 8; ++c) {
            float q = es[0][c] * eul[0];
            #pragma unroll
            for (int r = 1; r < 8; ++r) q = fmaf(es[r][c], eul[r], q);
            pc[c] = q;
        }
        #pragma unroll
        for (int c = 0; c < 8; ++c) pc[c] = xor32_add(pc[c]);  // fold a=2w with 2w+1
        us = xor32_add(us);

        if ((t & 32) == 0) {  // lanes 0..31 of each wave write row w
            float* dst = &sbuf[cur][w * PS];
            *reinterpret_cast<float4*>(dst + (bb << 2)) =
                make_float4(pc[0], pc[1], pc[2], pc[3]);
            *reinterpret_cast<float4*>(dst + 128 + (bb << 2)) =
                make_float4(pc[4], pc[5], pc[6], pc[7]);
            if (bb == 0) dst[256] = us;
        }
        __syncthreads();

        if (t < 514) {  // 2 threads per column: halves of the 16 wave-partials
            const int col = t >> 1;
            const int r0  = (t & 1) << 3;
            float q0 = 0.f, q1 = 0.f;
            #pragma unroll
            for (int k = 0; k < 8; k += 2) {
                q0 += sbuf[cur][(r0 + k) * PS + col];
                q1 += sbuf[cur][(r0 + k + 1) * PS + col];
            }
            float q = q0 + q1;
            q = dpp_add<0xB1>(q);  // combine lanes t, t^1 (both active)
            if ((t & 1) == 0) {
                vbuf[nxt][col] = (col < 256) ? (K9 / (q + A * eud))
                                             : (halfOverA / (q + eud));
            }
        }
        __syncthreads();
    }

    // ---------------- output: Z = (s' + u' + v' + 9)*ln2 ----------------
    const int fin = iters & 1;
    const float vdust = flog2(vbuf[fin][256]);
    const float udust = flog2(eud);
    const float4 f0 = *reinterpret_cast<const float4*>(&vbuf[fin][bb << 2]);
    const float4 f1 = *reinterpret_cast<const float4*>(&vbuf[fin][128 + (bb << 2)]);
    float vl[8] = {flog2(f0.x), flog2(f0.y), flog2(f0.z), flog2(f0.w),
                   flog2(f1.x), flog2(f1.y), flog2(f1.z), flog2(f1.w)};

    const size_t ob = (size_t)bat * 66049;  // 257*257
    #pragma unroll
    for (int r = 0; r < 8; ++r) {
        const float up = flog2(eul[r]);
        const float su = up + 9.0f;
        float* rp = out + ob + (size_t)((a << 3) + r) * 257;
        #pragma unroll
        for (int c = 0; c < 4; ++c)
            rp[(bb << 2) + c] = (flog2(es[r][c]) + su + vl[c]) * LN2;
        #pragma unroll
        for (int c = 4; c < 8; ++c)
            rp[128 + (bb << 2) + (c - 4)] = (flog2(es[r][c]) + su + vl[c]) * LN2;
        if (bb == 0) rp[256] = (alpha2 + up + vdust + 9.0f) * LN2;  // dustbin col
    }
    // dustbin row (i=256), incl. corner at j=256
    if (t < 257) {
        const float vp = (t < 256) ? flog2(vbuf[fin][t]) : vdust;
        out[ob + 65792 + t] = (alpha2 + udust + vp + 9.0f) * LN2;
    }
}

extern "C" void kernel_launch(void* const* d_in, const int* in_sizes, int n_in,
                              void* d_out, int out_size, void* d_ws, size_t ws_size,
                              hipStream_t stream)
{
    const float* scores = (const float*)d_in[0];
    const float* alpha  = (const float*)d_in[1];
    const int*   iters  = (const int*)d_in[2];
    float* out = (float*)d_out;
    const int B = in_sizes[0] >> 16;
    hipLaunchKernelGGL(sinkhorn_kernel, dim3(B), dim3(1024), 0, stream,
                       scores, alpha, iters, out);
}

// Round 6
// 176.835 us; speedup vs baseline: 2.3116x; 2.3116x over previous
//
#include <hip/hip_runtime.h>
#include <hip/hip_fp16.h>

// Sinkhorn (dustbin-augmented) fully fused, EXP-domain iteration, with the
// score tile RESIDENT IN LDS as packed f16 (the register allocator remats /
// spills any 64-float per-thread array no matter what occupancy attributes
// say -- v1..v5 all ran at VGPR_Count<=64 re-fetching scores from HBM, 910 MB
// fetch, 437 us).
//
//   ev_j = 2^{v'_j}, eu_i = 2^{u'_i}, A = 2^{alpha*log2e}, K9 = 2^-9
//   eu_i  = K9 / (sum_j es_ij*ev_j + A*evd)        es_ij = 2^{s_ij*log2e}
//   eud   = (0.5/A) / (sum_j ev_j + evd)
//   ev_j  = K9 / (sum_i es_ij*eu_i + A*eud)
//   evd   = (0.5/A) / (sum_i eu_i + eud)
//   Z     = (log2(es) + log2(eu) + log2(ev) + 9) * ln2
//
// Block = 1024 threads = one batch. Thread (a=t>>5, bb=t&31) owns rows
// [8a,8a+8) x cols {4bb..4bb+3, 128+4bb..128+4bb+3}. Its 64 es values are
// stored as 8 x uint4 (8 f16 each) at esl[r][t]: wave-contiguous 16B lanes ->
// canonical conflict-free ds_read_b128. Each chunk is read ONCE per
// iteration (row-sum and col-accumulate fused).

#define PS 260  // sbuf row stride in floats

constexpr float L2E = 1.4426950408889634f;
constexpr float LN2 = 0.6931471805599453f;
constexpr float K9  = 0.001953125f;  // 2^-9

__device__ __forceinline__ float flog2(float x) { return __builtin_amdgcn_logf(x); }
__device__ __forceinline__ float fexp2(float x) { return __builtin_amdgcn_exp2f(x); }

template <int CTRL>
__device__ __forceinline__ float dpp_add(float x) {
    int y = __builtin_amdgcn_update_dpp(0, __builtin_bit_cast(int, x), CTRL, 0xF, 0xF, true);
    return x + __builtin_bit_cast(float, y);
}

// allreduce over the 32 lanes of a half-wave (the bb dimension)
__device__ __forceinline__ float reduce32(float x) {
    x = dpp_add<0xB1>(x);    // quad_perm [1,0,3,2] : xor 1
    x = dpp_add<0x4E>(x);    // quad_perm [2,3,0,1] : xor 2
    x = dpp_add<0x124>(x);   // row_ror:4           : quad fold
    x = dpp_add<0x128>(x);   // row_ror:8           : row uniform
    x += __shfl_xor(x, 16, 64);  // cross 16
    return x;
}

__device__ __forceinline__ float xor32_add(float x) {
    return x + __shfl_xor(x, 32, 64);
}

__device__ __forceinline__ unsigned pack2h(float lo, float hi) {
    return (unsigned)__half_as_ushort(__float2half(lo)) |
           ((unsigned)__half_as_ushort(__float2half(hi)) << 16);
}

__global__ __launch_bounds__(1024) void sinkhorn_kernel(
    const float* __restrict__ scores,
    const float* __restrict__ alpha_p,
    const int*   __restrict__ iters_p,
    float* __restrict__ out)
{
    const int bat = blockIdx.x;
    const int t   = threadIdx.x;
    const int a   = t >> 5;   // row-group: rows [8a, 8a+8)
    const int bb  = t & 31;   // col-group: cols 4bb.. and 128+4bb..
    const int w   = t >> 6;   // wave id 0..15

    const float alpha2    = alpha_p[0] * L2E;
    const float A         = fexp2(alpha2);
    const float halfOverA = fexp2(-1.0f - alpha2);
    const int iters = iters_p[0];

    __shared__ uint4 esl[8][1024];                 // 128 KB f16 score tile
    __shared__ __align__(16) float sbuf[16 * PS];  // 16.6 KB wave partials
    __shared__ __align__(16) float vbuf[PS];       // 1 KB ev (257 used)

    // ---- load scores once; es = 2^(s*log2e) -> f16 chunks in LDS ----
    const float* sp = scores + ((size_t)bat << 16) + ((size_t)a << 11) + (bb << 2);
    #pragma unroll
    for (int r = 0; r < 8; ++r) {
        const float4 x0 = *reinterpret_cast<const float4*>(sp + (r << 8));
        const float4 x1 = *reinterpret_cast<const float4*>(sp + (r << 8) + 128);
        uint4 ch;
        ch.x = pack2h(fexp2(x0.x * L2E), fexp2(x0.y * L2E));
        ch.y = pack2h(fexp2(x0.z * L2E), fexp2(x0.w * L2E));
        ch.z = pack2h(fexp2(x1.x * L2E), fexp2(x1.y * L2E));
        ch.w = pack2h(fexp2(x1.z * L2E), fexp2(x1.w * L2E));
        esl[r][t] = ch;
    }

    if (t < 257) vbuf[t] = 1.0f;   // v0 = 0  ->  ev = 1
    float eul[8];
    #pragma unroll
    for (int r = 0; r < 8; ++r) eul[r] = 1.0f;
    float eud = 1.0f;
    __syncthreads();

    for (int it = 0; it < iters; ++it) {
        // ---- phase A: ev state + dustbin ----
        const float4 e0 = *reinterpret_cast<const float4*>(&vbuf[bb << 2]);
        const float4 e1 = *reinterpret_cast<const float4*>(&vbuf[128 + (bb << 2)]);
        const float evd = vbuf[256];
        float evl[8] = {e0.x, e0.y, e0.z, e0.w, e1.x, e1.y, e1.z, e1.w};

        float sv = ((evl[0]+evl[1])+(evl[2]+evl[3]))+((evl[4]+evl[5])+(evl[6]+evl[7]));
        sv = reduce32(sv);                       // sum_j ev_j (all 256 cols)
        eud = halfOverA / (sv + evd);

        // ---- phase B (fused): per chunk r -> p[r] -> eul[r] -> pc accumulate ----
        const float tdv = A * evd;
        float pc[8];
        #pragma unroll
        for (int c = 0; c < 8; ++c) pc[c] = 0.0f;
        float us = 0.0f;

        #pragma unroll
        for (int r = 0; r < 8; ++r) {
            const uint4 ch = esl[r][t];
            const __half* hp = reinterpret_cast<const __half*>(&ch);
            float p = __half2float(hp[0]) * evl[0];
            #pragma unroll
            for (int c = 1; c < 8; ++c) p = fmaf(__half2float(hp[c]), evl[c], p);
            p = reduce32(p);                     // uniform over 32 bb-lanes
            const float er = K9 / (p + tdv);
            eul[r] = er;
            us += er;
            #pragma unroll
            for (int c = 0; c < 8; ++c) pc[c] = fmaf(__half2float(hp[c]), er, pc[c]);
        }

        #pragma unroll
        for (int c = 0; c < 8; ++c) pc[c] = xor32_add(pc[c]);  // fold a=2w with 2w+1
        us = xor32_add(us);

        if ((t & 32) == 0) {  // lanes 0..31 of each wave write row w
            float* dst = &sbuf[w * PS];
            *reinterpret_cast<float4*>(dst + (bb << 2)) =
                make_float4(pc[0], pc[1], pc[2], pc[3]);
            *reinterpret_cast<float4*>(dst + 128 + (bb << 2)) =
                make_float4(pc[4], pc[5], pc[6], pc[7]);
            if (bb == 0) dst[256] = us;
        }
        __syncthreads();

        // ---- phase C: cross-wave column reduce, new ev ----
        if (t < 514) {  // 2 threads per column: halves of the 16 wave-partials
            const int col = t >> 1;
            const int r0  = (t & 1) << 3;
            float q0 = 0.f, q1 = 0.f;
            #pragma unroll
            for (int k = 0; k < 8; k += 2) {
                q0 += sbuf[(r0 + k) * PS + col];
                q1 += sbuf[(r0 + k + 1) * PS + col];
            }
            float q = q0 + q1;
            q = dpp_add<0xB1>(q);  // combine lanes t, t^1 (both active)
            if ((t & 1) == 0) {
                vbuf[col] = (col < 256) ? (K9 / (q + A * eud))
                                        : (halfOverA / (q + eud));
            }
        }
        __syncthreads();
    }

    // ---------------- output: Z = (s' + u' + v' + 9)*ln2 ----------------
    const float vdust = flog2(vbuf[256]);
    const float udust = flog2(eud);
    const float4 f0 = *reinterpret_cast<const float4*>(&vbuf[bb << 2]);
    const float4 f1 = *reinterpret_cast<const float4*>(&vbuf[128 + (bb << 2)]);
    float vl[8] = {flog2(f0.x), flog2(f0.y), flog2(f0.z), flog2(f0.w),
                   flog2(f1.x), flog2(f1.y), flog2(f1.z), flog2(f1.w)};

    const size_t ob = (size_t)bat * 66049;  // 257*257
    #pragma unroll
    for (int r = 0; r < 8; ++r) {
        const uint4 ch = esl[r][t];
        const __half* hp = reinterpret_cast<const __half*>(&ch);
        const float up = flog2(eul[r]);
        const float su = up + 9.0f;
        float* rp = out + ob + (size_t)((a << 3) + r) * 257;
        #pragma unroll
        for (int c = 0; c < 4; ++c)
            rp[(bb << 2) + c] = (flog2(__half2float(hp[c])) + su + vl[c]) * LN2;
        #pragma unroll
        for (int c = 4; c < 8; ++c)
            rp[128 + (bb << 2) + (c - 4)] = (flog2(__half2float(hp[c])) + su + vl[c]) * LN2;
        if (bb == 0) rp[256] = (alpha2 + up + vdust + 9.0f) * LN2;  // dustbin col
    }
    // dustbin row (i=256), incl. corner at j=256
    if (t < 257) {
        const float vp = (t < 256) ? flog2(vbuf[t]) : vdust;
        out[ob + 65792 + t] = (alpha2 + udust + vp + 9.0f) * LN2;
    }
}

extern "C" void kernel_launch(void* const* d_in, const int* in_sizes, int n_in,
                              void* d_out, int out_size, void* d_ws, size_t ws_size,
                              hipStream_t stream)
{
    const float* scores = (const float*)d_in[0];
    const float* alpha  = (const float*)d_in[1];
    const int*   iters  = (const int*)d_in[2];
    float* out = (float*)d_out;
    const int B = in_sizes[0] >> 16;
    hipLaunchKernelGGL(sinkhorn_kernel, dim3(B), dim3(1024), 0, stream,
                       scores, alpha, iters, out);
}

// Round 7
// 158.812 us; speedup vs baseline: 2.5740x; 1.1135x over previous
//
#include <hip/hip_runtime.h>
#include <hip/hip_fp16.h>

// Sinkhorn (dustbin-augmented) fully fused, EXP-domain iteration, score tile
// resident in LDS as packed f16 (v6 structure). v7: exact f32 divisions in
// the hot loop replaced by v_rcp_f32 + 1 Newton step (<=1 ulp), and the
// xor16 step of the 32-lane reduction moved from ds_bpermute (__shfl_xor) to
// ds_swizzle 0x401F (no address VGPRs, canonical butterfly).
//
//   ev_j = 2^{v'_j}, eu_i = 2^{u'_i}, A = 2^{alpha*log2e}, K9 = 2^-9
//   eu_i  = K9 / (sum_j es_ij*ev_j + A*evd)        es_ij = 2^{s_ij*log2e}
//   eud   = (0.5/A) / (sum_j ev_j + evd)
//   ev_j  = K9 / (sum_i es_ij*eu_i + A*eud)
//   evd   = (0.5/A) / (sum_i eu_i + eud)
//   Z     = (log2(es) + log2(eu) + log2(ev) + 9) * ln2
//
// Block = 1024 threads = one batch. Thread (a=t>>5, bb=t&31) owns rows
// [8a,8a+8) x cols {4bb..4bb+3, 128+4bb..128+4bb+3}; its 64 es values live
// as 8 x uint4 (8 f16) at esl[r][t] (wave-contiguous 16B -> conflict-free
// ds_read_b128), read ONCE per iteration (row-sum and col-accumulate fused).

#define PS 260  // sbuf row stride in floats

constexpr float L2E = 1.4426950408889634f;
constexpr float LN2 = 0.6931471805599453f;
constexpr float K9  = 0.001953125f;  // 2^-9

__device__ __forceinline__ float flog2(float x) { return __builtin_amdgcn_logf(x); }
__device__ __forceinline__ float fexp2(float x) { return __builtin_amdgcn_exp2f(x); }

// 1/d via v_rcp_f32 + one Newton-Raphson step: |err| < 1 ulp, d > 0 here.
__device__ __forceinline__ float rcp_nr(float d) {
    float r = __builtin_amdgcn_rcpf(d);
    return r * fmaf(-d, r, 2.0f);
}

template <int CTRL>
__device__ __forceinline__ float dpp_add(float x) {
    int y = __builtin_amdgcn_update_dpp(0, __builtin_bit_cast(int, x), CTRL, 0xF, 0xF, true);
    return x + __builtin_bit_cast(float, y);
}

// allreduce over the 32 lanes of a half-wave (the bb dimension)
__device__ __forceinline__ float reduce32(float x) {
    x = dpp_add<0xB1>(x);    // quad_perm [1,0,3,2] : xor 1
    x = dpp_add<0x4E>(x);    // quad_perm [2,3,0,1] : xor 2
    x = dpp_add<0x124>(x);   // row_ror:4           : quad fold
    x = dpp_add<0x128>(x);   // row_ror:8           : row uniform
    {                        // cross 16: ds_swizzle xor-16 (BitMode)
        int y = __builtin_amdgcn_ds_swizzle(__builtin_bit_cast(int, x), 0x401F);
        x += __builtin_bit_cast(float, y);
    }
    return x;
}

__device__ __forceinline__ float xor32_add(float x) {
    return x + __shfl_xor(x, 32, 64);  // proven path
}

__device__ __forceinline__ unsigned pack2h(float lo, float hi) {
    return (unsigned)__half_as_ushort(__float2half(lo)) |
           ((unsigned)__half_as_ushort(__float2half(hi)) << 16);
}

__global__ __launch_bounds__(1024) void sinkhorn_kernel(
    const float* __restrict__ scores,
    const float* __restrict__ alpha_p,
    const int*   __restrict__ iters_p,
    float* __restrict__ out)
{
    const int bat = blockIdx.x;
    const int t   = threadIdx.x;
    const int a   = t >> 5;   // row-group: rows [8a, 8a+8)
    const int bb  = t & 31;   // col-group: cols 4bb.. and 128+4bb..
    const int w   = t >> 6;   // wave id 0..15

    const float alpha2    = alpha_p[0] * L2E;
    const float A         = fexp2(alpha2);
    const float halfOverA = fexp2(-1.0f - alpha2);
    const int iters = iters_p[0];

    __shared__ uint4 esl[8][1024];                 // 128 KB f16 score tile
    __shared__ __align__(16) float sbuf[16 * PS];  // 16.6 KB wave partials
    __shared__ __align__(16) float vbuf[PS];       // 1 KB ev (257 used)

    // ---- load scores once; es = 2^(s*log2e) -> f16 chunks in LDS ----
    const float* sp = scores + ((size_t)bat << 16) + ((size_t)a << 11) + (bb << 2);
    #pragma unroll
    for (int r = 0; r < 8; ++r) {
        const float4 x0 = *reinterpret_cast<const float4*>(sp + (r << 8));
        const float4 x1 = *reinterpret_cast<const float4*>(sp + (r << 8) + 128);
        uint4 ch;
        ch.x = pack2h(fexp2(x0.x * L2E), fexp2(x0.y * L2E));
        ch.y = pack2h(fexp2(x0.z * L2E), fexp2(x0.w * L2E));
        ch.z = pack2h(fexp2(x1.x * L2E), fexp2(x1.y * L2E));
        ch.w = pack2h(fexp2(x1.z * L2E), fexp2(x1.w * L2E));
        esl[r][t] = ch;
    }

    if (t < 257) vbuf[t] = 1.0f;   // v0 = 0  ->  ev = 1
    float eul[8];
    #pragma unroll
    for (int r = 0; r < 8; ++r) eul[r] = 1.0f;
    float eud = 1.0f;
    __syncthreads();

    for (int it = 0; it < iters; ++it) {
        // ---- phase A: ev state + dustbin ----
        const float4 e0 = *reinterpret_cast<const float4*>(&vbuf[bb << 2]);
        const float4 e1 = *reinterpret_cast<const float4*>(&vbuf[128 + (bb << 2)]);
        const float evd = vbuf[256];
        float evl[8] = {e0.x, e0.y, e0.z, e0.w, e1.x, e1.y, e1.z, e1.w};

        float sv = ((evl[0]+evl[1])+(evl[2]+evl[3]))+((evl[4]+evl[5])+(evl[6]+evl[7]));
        sv = reduce32(sv);                       // sum_j ev_j (all 256 cols)
        eud = halfOverA * rcp_nr(sv + evd);

        // ---- phase B (fused): per chunk r -> p[r] -> eul[r] -> pc accumulate ----
        const float tdv = A * evd;
        float pc[8];
        #pragma unroll
        for (int c = 0; c < 8; ++c) pc[c] = 0.0f;
        float us = 0.0f;

        #pragma unroll
        for (int r = 0; r < 8; ++r) {
            const uint4 ch = esl[r][t];
            const __half* hp = reinterpret_cast<const __half*>(&ch);
            float p = __half2float(hp[0]) * evl[0];
            #pragma unroll
            for (int c = 1; c < 8; ++c) p = fmaf(__half2float(hp[c]), evl[c], p);
            p = reduce32(p);                     // uniform over 32 bb-lanes
            const float er = K9 * rcp_nr(p + tdv);
            eul[r] = er;
            us += er;
            #pragma unroll
            for (int c = 0; c < 8; ++c) pc[c] = fmaf(__half2float(hp[c]), er, pc[c]);
        }

        #pragma unroll
        for (int c = 0; c < 8; ++c) pc[c] = xor32_add(pc[c]);  // fold a=2w with 2w+1
        us = xor32_add(us);

        if ((t & 32) == 0) {  // lanes 0..31 of each wave write row w
            float* dst = &sbuf[w * PS];
            *reinterpret_cast<float4*>(dst + (bb << 2)) =
                make_float4(pc[0], pc[1], pc[2], pc[3]);
            *reinterpret_cast<float4*>(dst + 128 + (bb << 2)) =
                make_float4(pc[4], pc[5], pc[6], pc[7]);
            if (bb == 0) dst[256] = us;
        }
        __syncthreads();

        // ---- phase C: cross-wave column reduce, new ev ----
        if (t < 514) {  // 2 threads per column: halves of the 16 wave-partials
            const int col = t >> 1;
            const int r0  = (t & 1) << 3;
            float q0 = 0.f, q1 = 0.f;
            #pragma unroll
            for (int k = 0; k < 8; k += 2) {
                q0 += sbuf[(r0 + k) * PS + col];
                q1 += sbuf[(r0 + k + 1) * PS + col];
            }
            float q = q0 + q1;
            q = dpp_add<0xB1>(q);  // combine lanes t, t^1 (both active)
            if ((t & 1) == 0) {
                vbuf[col] = (col < 256) ? (K9 * rcp_nr(q + A * eud))
                                        : (halfOverA * rcp_nr(q + eud));
            }
        }
        __syncthreads();
    }

    // ---------------- output: Z = (s' + u' + v' + 9)*ln2 ----------------
    const float vdust = flog2(vbuf[256]);
    const float udust = flog2(eud);
    const float4 f0 = *reinterpret_cast<const float4*>(&vbuf[bb << 2]);
    const float4 f1 = *reinterpret_cast<const float4*>(&vbuf[128 + (bb << 2)]);
    float vl[8] = {flog2(f0.x), flog2(f0.y), flog2(f0.z), flog2(f0.w),
                   flog2(f1.x), flog2(f1.y), flog2(f1.z), flog2(f1.w)};

    const size_t ob = (size_t)bat * 66049;  // 257*257
    #pragma unroll
    for (int r = 0; r < 8; ++r) {
        const uint4 ch = esl[r][t];
        const __half* hp = reinterpret_cast<const __half*>(&ch);
        const float up = flog2(eul[r]);
        const float su = up + 9.0f;
        float* rp = out + ob + (size_t)((a << 3) + r) * 257;
        #pragma unroll
        for (int c = 0; c < 4; ++c)
            rp[(bb << 2) + c] = (flog2(__half2float(hp[c])) + su + vl[c]) * LN2;
        #pragma unroll
        for (int c = 4; c < 8; ++c)
            rp[128 + (bb << 2) + (c - 4)] = (flog2(__half2float(hp[c])) + su + vl[c]) * LN2;
        if (bb == 0) rp[256] = (alpha2 + up + vdust + 9.0f) * LN2;  // dustbin col
    }
    // dustbin row (i=256), incl. corner at j=256
    if (t < 257) {
        const float vp = (t < 256) ? flog2(vbuf[t]) : vdust;
        out[ob + 65792 + t] = (alpha2 + udust + vp + 9.0f) * LN2;
    }
}

extern "C" void kernel_launch(void* const* d_in, const int* in_sizes, int n_in,
                              void* d_out, int out_size, void* d_ws, size_t ws_size,
                              hipStream_t stream)
{
    const float* scores = (const float*)d_in[0];
    const float* alpha  = (const float*)d_in[1];
    const int*   iters  = (const int*)d_in[2];
    float* out = (float*)d_out;
    const int B = in_sizes[0] >> 16;
    hipLaunchKernelGGL(sinkhorn_kernel, dim3(B), dim3(1024), 0, stream,
                       scores, alpha, iters, out);
}

// Round 8
// 112.873 us; speedup vs baseline: 3.6216x; 1.4070x over previous
//
#include <hip/hip_runtime.h>

// Sinkhorn (dustbin-augmented), MFMA edition.
//
// Scaled exp-domain state (K9 = 2^-9, A = 2^{alpha*log2e}, C = 2^8/A):
//   EU_i = 1/(sum_j es_ij*EV_j + A*evd)         es = 2^{s*log2e} (f16)
//   eud_s = C/(sum_j EV_j + evd)
//   EV_j = 1/(sum_i es_ij*EU_i + A*eud_s)
//   evd' = C/(sum_i EU_i + eud_s)
//   Z core      = (log2 es + log2 EU + log2 EV) * ln2
//   Z col-dust  = (alpha2 + log2 EU + log2 evd) * ln2
//   Z row-dust  = (alpha2 + log2 eud_s + log2 EV) * ln2
//   Z corner    = (alpha2 + log2 eud_s + log2 evd) * ln2
//
// Both matvecs run on the matrix pipe via mfma_f32_16x16x32_f16 with a
// replicated operand:  p-phase  D[m][n] = sum_k es[m][k] * EV[k]  (B repl.)
//                      q-phase  D[m][n] = sum_k EU[k] * es[k][n]  (A repl.)
// es lives in LDS column-major, XOR-swizzled (elem k ^ ((col&7)<<3)) so the
// q-phase column fragments are conflict-free ds_read_b128. The p-phase row
// fragments are loaded ONCE into 32 persistent VGPRs (asm-pinned: the
// allocator remats/spills any rematerializable 64-elem array -- v3..v5).
// Any error in the assumed A/B k-mapping cancels (A,B share the lane->k
// map); the C/D layout used is the HW-measured one (col=lane&15,
// row=(lane>>4)*4+reg).

typedef _Float16 half8 __attribute__((ext_vector_type(8)));
typedef float floatx4 __attribute__((ext_vector_type(4)));

constexpr float L2E = 1.4426950408889634f;
constexpr float LN2 = 0.6931471805599453f;

__device__ __forceinline__ float flog2(float x) { return __builtin_amdgcn_logf(x); }
__device__ __forceinline__ float fexp2(float x) { return __builtin_amdgcn_exp2f(x); }

// 1/d via v_rcp_f32 + one Newton step (<=1 ulp, d>0)
__device__ __forceinline__ float rcp_nr(float d) {
    float r = __builtin_amdgcn_rcpf(d);
    return r * fmaf(-d, r, 2.0f);
}

template <int CTRL>
__device__ __forceinline__ float dpp_add(float x) {
    int y = __builtin_amdgcn_update_dpp(0, __builtin_bit_cast(int, x), CTRL, 0xF, 0xF, true);
    return x + __builtin_bit_cast(float, y);
}
// sum over the 16 lanes of each row (lanes l&15)
__device__ __forceinline__ float reduce16(float x) {
    x = dpp_add<0xB1>(x);    // xor 1
    x = dpp_add<0x4E>(x);    // xor 2
    x = dpp_add<0x124>(x);   // row_ror:4
    x = dpp_add<0x128>(x);   // row_ror:8
    return x;
}
__device__ __forceinline__ float xor16_add(float x) {
    int y = __builtin_amdgcn_ds_swizzle(__builtin_bit_cast(int, x), 0x401F);
    return x + __builtin_bit_cast(float, y);
}

__global__ __launch_bounds__(1024)
__attribute__((amdgpu_waves_per_eu(4, 4)))
void sinkhorn_kernel(const float* __restrict__ scores,
                     const float* __restrict__ alpha_p,
                     const int* __restrict__ iters_p,
                     float* __restrict__ out)
{
    const int bat = blockIdx.x;
    const int t   = threadIdx.x;
    const int a   = t >> 5;         // prologue/epilogue: rows [8a, 8a+8)
    const int bb  = t & 31;         // prologue/epilogue: cols 4bb.. / 128+4bb..
    const int w   = t >> 6;         // wave 0..15
    const int l   = t & 63;
    const int g   = (t >> 4) & 3;   // k-group within wave
    const int l15 = t & 15;

    const float alpha2 = alpha_p[0] * L2E;
    const float A  = fexp2(alpha2);
    const float Cs = fexp2(8.0f - alpha2);   // 2^8 / A
    const int iters = iters_p[0];

    __shared__ __align__(16) unsigned short esT[65536];  // 128 KB, col-major swizzled
    __shared__ __align__(16) unsigned short EUa[272];
    __shared__ __align__(16) unsigned short EVa[272];
    __shared__ __align__(16) float wsU[16];
    __shared__ __align__(16) float wsV[16];

    // ---------------- prologue: load scores -> f16 es^T (swizzled) ----------------
    {
        const float* sp = scores + ((size_t)bat << 16) + ((size_t)a << 11) + (bb << 2);
        half8 cp[8];  // per-column packs of this thread's 8 rows
        #pragma unroll
        for (int r = 0; r < 8; ++r) {
            const float4 x0 = *reinterpret_cast<const float4*>(sp + (r << 8));
            const float4 x1 = *reinterpret_cast<const float4*>(sp + (r << 8) + 128);
            cp[0][r] = (_Float16)fexp2(x0.x * L2E);
            cp[1][r] = (_Float16)fexp2(x0.y * L2E);
            cp[2][r] = (_Float16)fexp2(x0.z * L2E);
            cp[3][r] = (_Float16)fexp2(x0.w * L2E);
            cp[4][r] = (_Float16)fexp2(x1.x * L2E);
            cp[5][r] = (_Float16)fexp2(x1.y * L2E);
            cp[6][r] = (_Float16)fexp2(x1.z * L2E);
            cp[7][r] = (_Float16)fexp2(x1.w * L2E);
        }
        #pragma unroll
        for (int ci = 0; ci < 8; ++ci) {
            const int col = (ci < 4) ? ((bb << 2) + ci) : (128 + (bb << 2) + ci - 4);
            const int idx = (col << 8) + (((a << 3)) ^ ((col & 7) << 3));
            *reinterpret_cast<half8*>(&esT[idx]) = cp[ci];
        }
    }
    if (t < 256) EVa[t] = 0x3C00;      // EV = 1.0 (f16)
    if (t < 16)  wsV[t] = 16.0f;       // per-wave sum of 16 ones
    __syncthreads();

    // ---- persistent A-fragments: es rows strip of wave w (asm-pinned) ----
    half8 esA[8];
    {
        const int m16 = (w << 4) + l15;
        #pragma unroll
        for (int s = 0; s < 8; ++s) {
            #pragma unroll
            for (int j = 0; j < 8; ++j) {
                const int col = (s << 5) + (g << 3) + j;
                const unsigned short v =
                    esT[(col << 8) + (m16 ^ ((col & 7) << 3))];
                esA[s][j] = __builtin_bit_cast(_Float16, v);
            }
            asm volatile("" : "+v"(esA[s]));  // opaque def: no remat
        }
    }

    float evd = 1.0f, eud_s = 1.0f;

    for (int it = 0; it < iters; ++it) {
        // ---- scalars: eud_s from Sum(EV) + evd (all threads, redundant) ----
        float sv = evd;
        {
            const floatx4* wv = reinterpret_cast<const floatx4*>(wsV);
            floatx4 s0 = wv[0], s1 = wv[1], s2 = wv[2], s3 = wv[3];
            floatx4 ss = (s0 + s1) + (s2 + s3);
            sv += (ss[0] + ss[1]) + (ss[2] + ss[3]);
        }
        eud_s = Cs * rcp_nr(sv);
        const float tdu = A * eud_s;
        const float tdv = A * evd;

        // ---- p-phase: D[m][*] = sum_k es[m][k]*EV[k] ----
        floatx4 acc = {0.f, 0.f, 0.f, 0.f};
        const half8* evp = reinterpret_cast<const half8*>(EVa) + g;
        #pragma unroll
        for (int s = 0; s < 8; ++s)
            acc = __builtin_amdgcn_mfma_f32_16x16x32_f16(esA[s], evp[s << 2], acc, 0, 0, 0);

        const float E0 = rcp_nr(acc[0] + tdv);
        const float E1 = rcp_nr(acc[1] + tdv);
        const float E2 = rcp_nr(acc[2] + tdv);
        const float E3 = rcp_nr(acc[3] + tdv);
        if (l15 < 4) {  // rows 16w + 4g + l15
            const float lo = (l15 & 1) ? E1 : E0;
            const float hi = (l15 & 1) ? E3 : E2;
            const float val = (l15 & 2) ? hi : lo;
            EUa[(w << 4) + (g << 2) + l15] =
                __builtin_bit_cast(unsigned short, (_Float16)val);
        }
        float sU = (E0 + E1) + (E2 + E3);
        sU = xor16_add(sU);
        sU += __shfl_xor(sU, 32, 64);
        if (l == 0) wsU[w] = sU;
        __syncthreads();

        // ---- scalars: evd' from Sum(EU) + eud_s ----
        float su = eud_s;
        {
            const floatx4* wu = reinterpret_cast<const floatx4*>(wsU);
            floatx4 s0 = wu[0], s1 = wu[1], s2 = wu[2], s3 = wu[3];
            floatx4 ss = (s0 + s1) + (s2 + s3);
            su += (ss[0] + ss[1]) + (ss[2] + ss[3]);
        }
        evd = Cs * rcp_nr(su);

        // ---- q-phase: D[*][n] = sum_k EU[k]*es[k][n] ----
        floatx4 acc2 = {0.f, 0.f, 0.f, 0.f};
        const int cbase = ((w << 4) + l15) << 8;
        const int swq = (l15 & 7) << 3;
        const half8* eup = reinterpret_cast<const half8*>(EUa) + g;
        #pragma unroll
        for (int s = 0; s < 8; ++s) {
            const half8 bq = *reinterpret_cast<const half8*>(
                &esT[cbase + (((s << 5) + (g << 3)) ^ swq)]);
            acc2 = __builtin_amdgcn_mfma_f32_16x16x32_f16(eup[s << 2], bq, acc2, 0, 0, 0);
        }
        const float EVv = rcp_nr(acc2[0] + tdu);   // col 16w + l15 (regs replicated)
        if (l < 16) EVa[(w << 4) + l] =
            __builtin_bit_cast(unsigned short, (_Float16)EVv);
        float sV = reduce16(EVv);
        if (l == 0) wsV[w] = sV;
        __syncthreads();
    }

    // ---------------- epilogue ----------------
    const float Ud = flog2(eud_s);
    const float Vd = flog2(evd);
    float Up[8], Vp[8];
    int cols[8];
    #pragma unroll
    for (int r = 0; r < 8; ++r)
        Up[r] = flog2((float)__builtin_bit_cast(_Float16, EUa[(a << 3) + r]));
    #pragma unroll
    for (int ci = 0; ci < 8; ++ci) {
        cols[ci] = (ci < 4) ? ((bb << 2) + ci) : (128 + (bb << 2) + ci - 4);
        Vp[ci] = flog2((float)__builtin_bit_cast(_Float16, EVa[cols[ci]]));
    }
    const size_t ob = (size_t)bat * 66049;  // 257*257
    #pragma unroll
    for (int ci = 0; ci < 8; ++ci) {
        const int col = cols[ci];
        const half8 esc = *reinterpret_cast<const half8*>(
            &esT[(col << 8) + ((a << 3) ^ ((col & 7) << 3))]);
        #pragma unroll
        for (int r = 0; r < 8; ++r) {
            out[ob + (size_t)((a << 3) + r) * 257 + col] =
                (flog2((float)esc[r]) + Up[r] + Vp[ci]) * LN2;
        }
    }
    if (bb == 0) {
        #pragma unroll
        for (int r = 0; r < 8; ++r)
            out[ob + (size_t)((a << 3) + r) * 257 + 256] =
                (alpha2 + Up[r] + Vd) * LN2;
    }
    if (t < 257) {
        const float vp = (t < 256)
            ? flog2((float)__builtin_bit_cast(_Float16, EVa[t])) : Vd;
        out[ob + 65792 + t] = (alpha2 + Ud + vp) * LN2;
    }
}

extern "C" void kernel_launch(void* const* d_in, const int* in_sizes, int n_in,
                              void* d_out, int out_size, void* d_ws, size_t ws_size,
                              hipStream_t stream)
{
    const float* scores = (const float*)d_in[0];
    const float* alpha  = (const float*)d_in[1];
    const int*   iters  = (const int*)d_in[2];
    float* out = (float*)d_out;
    const int B = in_sizes[0] >> 16;
    hipLaunchKernelGGL(sinkhorn_kernel, dim3(B), dim3(1024), 0, stream,
                       scores, alpha, iters, out);
}

// Round 9
// 103.173 us; speedup vs baseline: 3.9621x; 1.0940x over previous
//
#include <hip/hip_runtime.h>

// Sinkhorn (dustbin-augmented), MFMA edition, all matrix operands in VGPRs.
//
// Scaled exp-domain state (A = 2^{alpha*log2e}, C = 2^8/A):
//   EU_i = 1/(sum_j es_ij*EV_j + A*evd)         es = 2^{s*log2e} (f16)
//   eud_s = C/(sum_j EV_j + evd)
//   EV_j = 1/(sum_i es_ij*EU_i + A*eud_s)
//   evd' = C/(sum_i EU_i + eud_s)
//   Z core      = (log2 es + log2 EU + log2 EV) * ln2   (dustbins use alpha2)
//
// Both matvecs on the matrix pipe via mfma_f32_16x16x32_f16 with a replicated
// operand (p-phase: B[k][n]=EV[k]; q-phase: A[m][k]=EU[k]). v8 re-read the
// 128KB esT from LDS every iteration in the q-phase (8-way bank conflict,
// 9.7M conflict cycles = the bottleneck). v9 loads BOTH fragment sets once:
//   esA[8]: rows strip  (lane l15,g: a[j]=es[16w+l15][s*32+g*8+j])  32 VGPR
//   esB[8]: col strip   (lane l15,g: b[j]=es[s*32+g*8+j][16w+l15])  32 VGPR
// asm-pinned (the allocator remats any rematerializable array -- v3..v5).
// Iteration LDS traffic is just the 544B EU/EV vectors. MFMA chains split
// into 2x4-deep independent accumulators to halve dependent-MFMA latency.

typedef _Float16 half8 __attribute__((ext_vector_type(8)));
typedef float floatx4 __attribute__((ext_vector_type(4)));

constexpr float L2E = 1.4426950408889634f;
constexpr float LN2 = 0.6931471805599453f;

__device__ __forceinline__ float flog2(float x) { return __builtin_amdgcn_logf(x); }
__device__ __forceinline__ float fexp2(float x) { return __builtin_amdgcn_exp2f(x); }

// 1/d via v_rcp_f32 + one Newton step (<=1 ulp, d>0)
__device__ __forceinline__ float rcp_nr(float d) {
    float r = __builtin_amdgcn_rcpf(d);
    return r * fmaf(-d, r, 2.0f);
}

template <int CTRL>
__device__ __forceinline__ float dpp_add(float x) {
    int y = __builtin_amdgcn_update_dpp(0, __builtin_bit_cast(int, x), CTRL, 0xF, 0xF, true);
    return x + __builtin_bit_cast(float, y);
}
// sum over the 16 lanes of each row (lanes l&15)
__device__ __forceinline__ float reduce16(float x) {
    x = dpp_add<0xB1>(x);    // xor 1
    x = dpp_add<0x4E>(x);    // xor 2
    x = dpp_add<0x124>(x);   // row_ror:4
    x = dpp_add<0x128>(x);   // row_ror:8
    return x;
}
__device__ __forceinline__ float xor16_add(float x) {
    int y = __builtin_amdgcn_ds_swizzle(__builtin_bit_cast(int, x), 0x401F);
    return x + __builtin_bit_cast(float, y);
}

__global__ __launch_bounds__(1024)
__attribute__((amdgpu_waves_per_eu(4, 4)))
void sinkhorn_kernel(const float* __restrict__ scores,
                     const float* __restrict__ alpha_p,
                     const int* __restrict__ iters_p,
                     float* __restrict__ out)
{
    const int bat = blockIdx.x;
    const int t   = threadIdx.x;
    const int a   = t >> 5;         // prologue/epilogue: rows [8a, 8a+8)
    const int bb  = t & 31;         // prologue/epilogue: cols 4bb.. / 128+4bb..
    const int w   = t >> 6;         // wave 0..15
    const int l   = t & 63;
    const int g   = (t >> 4) & 3;   // k-group within wave
    const int l15 = t & 15;

    const float alpha2 = alpha_p[0] * L2E;
    const float A  = fexp2(alpha2);
    const float Cs = fexp2(8.0f - alpha2);   // 2^8 / A
    const int iters = iters_p[0];

    __shared__ __align__(16) unsigned short esT[65536];  // 128 KB, col-major swizzled
    __shared__ __align__(16) unsigned short EUa[272];
    __shared__ __align__(16) unsigned short EVa[272];
    __shared__ __align__(16) float wsU[16];
    __shared__ __align__(16) float wsV[16];

    // ---------------- prologue: load scores -> f16 es^T (swizzled) ----------------
    {
        const float* sp = scores + ((size_t)bat << 16) + ((size_t)a << 11) + (bb << 2);
        half8 cp[8];  // per-column packs of this thread's 8 rows
        #pragma unroll
        for (int r = 0; r < 8; ++r) {
            const float4 x0 = *reinterpret_cast<const float4*>(sp + (r << 8));
            const float4 x1 = *reinterpret_cast<const float4*>(sp + (r << 8) + 128);
            cp[0][r] = (_Float16)fexp2(x0.x * L2E);
            cp[1][r] = (_Float16)fexp2(x0.y * L2E);
            cp[2][r] = (_Float16)fexp2(x0.z * L2E);
            cp[3][r] = (_Float16)fexp2(x0.w * L2E);
            cp[4][r] = (_Float16)fexp2(x1.x * L2E);
            cp[5][r] = (_Float16)fexp2(x1.y * L2E);
            cp[6][r] = (_Float16)fexp2(x1.z * L2E);
            cp[7][r] = (_Float16)fexp2(x1.w * L2E);
        }
        #pragma unroll
        for (int ci = 0; ci < 8; ++ci) {
            const int col = (ci < 4) ? ((bb << 2) + ci) : (128 + (bb << 2) + ci - 4);
            const int idx = (col << 8) + (((a << 3)) ^ ((col & 7) << 3));
            *reinterpret_cast<half8*>(&esT[idx]) = cp[ci];
        }
    }
    if (t < 256) EVa[t] = 0x3C00;      // EV = 1.0 (f16)
    if (t < 16)  wsV[t] = 16.0f;       // per-wave sum of 16 ones
    __syncthreads();

    // ---- persistent A-fragments: es row strip of wave w (asm-pinned) ----
    half8 esA[8];
    {
        const int m16 = (w << 4) + l15;
        #pragma unroll
        for (int s = 0; s < 8; ++s) {
            #pragma unroll
            for (int j = 0; j < 8; ++j) {
                const int col = (s << 5) + (g << 3) + j;
                const unsigned short v =
                    esT[(col << 8) + (m16 ^ ((col & 7) << 3))];
                esA[s][j] = __builtin_bit_cast(_Float16, v);
            }
            asm volatile("" : "+v"(esA[s]));  // opaque def: no remat
        }
    }
    // ---- persistent B-fragments: es col strip (b[j]=es[s*32+g*8+j][16w+l15]) ----
    half8 esB[8];
    {
        const int cbase = ((w << 4) + l15) << 8;
        const int swq = (l15 & 7) << 3;
        #pragma unroll
        for (int s = 0; s < 8; ++s) {
            esB[s] = *reinterpret_cast<const half8*>(
                &esT[cbase + (((s << 5) + (g << 3)) ^ swq)]);
            asm volatile("" : "+v"(esB[s]));  // opaque def: no remat
        }
    }

    float evd = 1.0f, eud_s = 1.0f;

    for (int it = 0; it < iters; ++it) {
        // ---- scalars: eud_s from Sum(EV) + evd (all threads, redundant) ----
        float sv = evd;
        {
            const floatx4* wv = reinterpret_cast<const floatx4*>(wsV);
            floatx4 s0 = wv[0], s1 = wv[1], s2 = wv[2], s3 = wv[3];
            floatx4 ss = (s0 + s1) + (s2 + s3);
            sv += (ss[0] + ss[1]) + (ss[2] + ss[3]);
        }
        eud_s = Cs * rcp_nr(sv);
        const float tdu = A * eud_s;
        const float tdv = A * evd;

        // ---- p-phase: D[m][*] = sum_k es[m][k]*EV[k] (2x4 indep chains) ----
        floatx4 acc0 = {0.f, 0.f, 0.f, 0.f}, acc1 = {0.f, 0.f, 0.f, 0.f};
        const half8* evp = reinterpret_cast<const half8*>(EVa) + g;
        #pragma unroll
        for (int s = 0; s < 4; ++s) {
            acc0 = __builtin_amdgcn_mfma_f32_16x16x32_f16(esA[2*s],   evp[(2*s) << 2],   acc0, 0, 0, 0);
            acc1 = __builtin_amdgcn_mfma_f32_16x16x32_f16(esA[2*s+1], evp[(2*s+1) << 2], acc1, 0, 0, 0);
        }
        floatx4 acc = acc0 + acc1;

        const float E0 = rcp_nr(acc[0] + tdv);
        const float E1 = rcp_nr(acc[1] + tdv);
        const float E2 = rcp_nr(acc[2] + tdv);
        const float E3 = rcp_nr(acc[3] + tdv);
        if (l15 < 4) {  // rows 16w + 4g + l15
            const float lo = (l15 & 1) ? E1 : E0;
            const float hi = (l15 & 1) ? E3 : E2;
            const float val = (l15 & 2) ? hi : lo;
            EUa[(w << 4) + (g << 2) + l15] =
                __builtin_bit_cast(unsigned short, (_Float16)val);
        }
        float sU = (E0 + E1) + (E2 + E3);
        sU = xor16_add(sU);
        sU += __shfl_xor(sU, 32, 64);
        if (l == 0) wsU[w] = sU;
        __syncthreads();

        // ---- scalars: evd' from Sum(EU) + eud_s ----
        float su = eud_s;
        {
            const floatx4* wu = reinterpret_cast<const floatx4*>(wsU);
            floatx4 s0 = wu[0], s1 = wu[1], s2 = wu[2], s3 = wu[3];
            floatx4 ss = (s0 + s1) + (s2 + s3);
            su += (ss[0] + ss[1]) + (ss[2] + ss[3]);
        }
        evd = Cs * rcp_nr(su);

        // ---- q-phase: D[*][n] = sum_k EU[k]*es[k][n] (2x4 indep chains) ----
        floatx4 q0 = {0.f, 0.f, 0.f, 0.f}, q1 = {0.f, 0.f, 0.f, 0.f};
        const half8* eup = reinterpret_cast<const half8*>(EUa) + g;
        #pragma unroll
        for (int s = 0; s < 4; ++s) {
            q0 = __builtin_amdgcn_mfma_f32_16x16x32_f16(eup[(2*s) << 2],   esB[2*s],   q0, 0, 0, 0);
            q1 = __builtin_amdgcn_mfma_f32_16x16x32_f16(eup[(2*s+1) << 2], esB[2*s+1], q1, 0, 0, 0);
        }
        floatx4 acc2 = q0 + q1;

        const float EVv = rcp_nr(acc2[0] + tdu);   // col 16w + l15 (regs replicated)
        if (l < 16) EVa[(w << 4) + l] =
            __builtin_bit_cast(unsigned short, (_Float16)EVv);
        float sV = reduce16(EVv);
        if (l == 0) wsV[w] = sV;
        __syncthreads();
    }

    // ---------------- epilogue ----------------
    const float Ud = flog2(eud_s);
    const float Vd = flog2(evd);
    float Up[8], Vp[8];
    int cols[8];
    #pragma unroll
    for (int r = 0; r < 8; ++r)
        Up[r] = flog2((float)__builtin_bit_cast(_Float16, EUa[(a << 3) + r]));
    #pragma unroll
    for (int ci = 0; ci < 8; ++ci) {
        cols[ci] = (ci < 4) ? ((bb << 2) + ci) : (128 + (bb << 2) + ci - 4);
        Vp[ci] = flog2((float)__builtin_bit_cast(_Float16, EVa[cols[ci]]));
    }
    const size_t ob = (size_t)bat * 66049;  // 257*257
    #pragma unroll
    for (int ci = 0; ci < 8; ++ci) {
        const int col = cols[ci];
        const half8 esc = *reinterpret_cast<const half8*>(
            &esT[(col << 8) + ((a << 3) ^ ((col & 7) << 3))]);
        #pragma unroll
        for (int r = 0; r < 8; ++r) {
            out[ob + (size_t)((a << 3) + r) * 257 + col] =
                (flog2((float)esc[r]) + Up[r] + Vp[ci]) * LN2;
        }
    }
    if (bb == 0) {
        #pragma unroll
        for (int r = 0; r < 8; ++r)
            out[ob + (size_t)((a << 3) + r) * 257 + 256] =
                (alpha2 + Up[r] + Vd) * LN2;
    }
    if (t < 257) {
        const float vp = (t < 256)
            ? flog2((float)__builtin_bit_cast(_Float16, EVa[t])) : Vd;
        out[ob + 65792 + t] = (alpha2 + Ud + vp) * LN2;
    }
}

extern "C" void kernel_launch(void* const* d_in, const int* in_sizes, int n_in,
                              void* d_out, int out_size, void* d_ws, size_t ws_size,
                              hipStream_t stream)
{
    const float* scores = (const float*)d_in[0];
    const float* alpha  = (const float*)d_in[1];
    const int*   iters  = (const int*)d_in[2];
    float* out = (float*)d_out;
    const int B = in_sizes[0] >> 16;
    hipLaunchKernelGGL(sinkhorn_kernel, dim3(B), dim3(1024), 0, stream,
                       scores, alpha, iters, out);
}